// Round 17
// baseline (167.793 us; speedup 1.0000x reference)
//
#include <hip/hip_runtime.h>
#include <hip/hip_bf16.h>
#include <limits.h>

typedef __attribute__((ext_vector_type(8))) short short8;
typedef __attribute__((ext_vector_type(4))) float f32x4;
typedef __attribute__((ext_vector_type(16))) float f32x16;

#define NN 8000
#define NCOL 4096      // 8*512 merged columns
#define KBINS 352      // NEST-1 == TOTAL_BINS
#define QPAD 640       // 583 padded
#define QH 320         // q rows per block (2 q-halves)
#define BN 256         // cols per block
#define KC 8           // k chunks (grid 16x2x8 = 256 blocks = 1/CU)
#define NTILE 64       // folded K padded: 64 tiles of 64 (n>4000 zeroed)
#define KSTEP 8        // tiles per chunk: 64 = 8*8 exact
#define CUTQ 4
#define T_ 512
#define WFB 64         // packed band width for W_freq
#define WQB 20         // packed band width for W_quef
#define NCB 640        // prep: cos blocks (1 q each)

#define GLL16(g, l) __builtin_amdgcn_global_load_lds( \
    (const __attribute__((address_space(1))) unsigned int*)(g), \
    (__attribute__((address_space(3))) unsigned int*)(l), 16, 0, 0)

static __device__ __forceinline__ ushort bfc(float f){
  __hip_bfloat16 h = __float2bfloat16(f);
  return *reinterpret_cast<ushort*>(&h);
}
static __device__ __forceinline__ float b2f(ushort u){
  unsigned v = ((unsigned)u) << 16; float f; __builtin_memcpy(&f, &v, 4); return f;
}

// prep: blocks [0,NCB): cos table cosg[kt][q][64-swizzled] bf16;
//       rest: bounds-scan + transposed band-pack of Wf/Wq.
__global__ __launch_bounds__(256) void prep_k(ushort* __restrict__ cosg,
        const float* __restrict__ Wf, const float* __restrict__ Wq,
        int HFI, int HQI, int* __restrict__ fLo, int* __restrict__ qLo,
        float* __restrict__ WfT, float* __restrict__ WqT){
  int blk = blockIdx.x, t = threadIdx.x;
  if (blk < NCB){
    int q = blk;
    int qz = (q < HQI) ? 1 : 0;
    #pragma unroll
    for (int h=0; h<2; ++h){                  // 2 octets per thread (16 n)
      int n0 = t*16 + h*8;                    // < 4096
      short8 o;
      #pragma unroll
      for (int e=0;e<8;e++){
        float v = 0.f;
        if (qz){
          int m = (q*(n0+e)) % NN;
          v = cosf((float)m * 7.8539816339744831e-4f);
        }
        o[e] = (short)bfc(v);
      }
      int kt = n0 >> 6, s8 = (n0 >> 3) & 7;
      *(short8*)(&cosg[(size_t)kt*(QPAD*64) + (size_t)q*64 + ((s8 ^ (q & 7)) << 3)]) = o;
    }
  } else {
    __shared__ int slo, shi;
    int u = blk - NCB;                        // 0..703
    int r = u >> 1;
    bool isF = (u & 1) == 0;
    const float* W = isF ? Wf : Wq;
    int width = isF ? HFI : HQI;
    int bw    = isF ? WFB : WQB;
    float* WT = isF ? WfT : WqT;
    int* Lo   = isF ? fLo : qLo;
    if (t==0){ slo = INT_MAX; shi = -1; }
    __syncthreads();
    int mylo = INT_MAX, myhi = -1;
    for (int c = t; c < width; c += 256){
      if (W[(size_t)r*width + c] != 0.f){ if (c < mylo) mylo = c; if (c > myhi) myhi = c; }
    }
    atomicMin(&slo, mylo); atomicMax(&shi, myhi);
    __syncthreads();
    int l = (shi < 0) ? 0 : slo, h = (shi < 0) ? 0 : shi + 1;
    if (t==0) Lo[r] = l;
    for (int j = t; j < bw; j += 256){
      float v = 0.f;
      if (l + j < h) v = W[(size_t)r*width + l + j];
      WT[(size_t)j*KBINS + r] = v;
    }
  }
}

// part[kc][col][q] (bf16) = sum_{k in chunk} xf[col][k]*cosg[q][k]
// where xf is the reflection fold computed IN-KERNEL during B staging:
//   xf[0]=x[0]; xf[n]=x[n]+x[8000-n] (1<=n<4000); xf[4000]=x[4000]; else 0.
// Block 320q x 256col, BK=64, 8 waves, wave tile 160q x 64col, dbuf 144KB LDS.
// A: GLL from pre-swizzled cosg. B: dx f32 -> 20 reg loads issued a FULL step
// early -> fold+cvt AFTER compute phases -> swizzled ds_write -> drain+barrier.
__global__ __launch_bounds__(512, 2) void gemm_k(const float* __restrict__ dx,
                                                 const ushort* __restrict__ cosg,
                                                 ushort* __restrict__ part){
  __shared__ ushort As[2][QH*64];    // cos tiles, 40 KB each, slot-swizzled
  __shared__ ushort Bs[2][BN*64];    // folded dx tiles, 32 KB each, slot-swizzled
  int tid = threadIdx.x;
  int nb = blockIdx.x, qh = blockIdx.y, kc = blockIdx.z;
  int lane = tid & 63, widx = tid >> 6;
  int wm = widx & 1, wn = widx >> 1;
  int l31 = lane & 31, lh = lane >> 5;
  int kt0 = kc*KSTEP, ktE = kt0 + KSTEP;

  const ushort* ag0 = cosg + (size_t)qh*(QH*64) + tid*8;
  int brow0 = tid >> 3, bs = tid & 7;        // 64 rows x 8 k-slots per pass; 4 passes
  const float* bp0 = dx + (size_t)(nb*BN + brow0)*NN;
  int bw0 = brow0*64 + ((bs ^ (brow0 & 7)) << 3);   // row&7 invariant under +64i

  f32x4 BF0[4], BF1[4], BMA[4], BMB[4];
  float BMS[4];

  #define AGLL(kt_, buf_) { \
    const ushort* ag_ = ag0 + (size_t)(kt_)*(QPAD*64); \
    _Pragma("unroll") \
    for (int i_=0;i_<5;i_++) GLL16(ag_ + i_*4096, &As[buf_][tid*8 + i_*4096]); }
  // 20 independent loads: fwd octet + aligned mirror window + guarded scalar
  #define BLOAD(kt_) { int n0_ = (kt_)*64 + bs*8; \
    _Pragma("unroll") \
    for (int i_=0;i_<4;i_++){ \
      const float* rp_ = bp0 + (size_t)i_*64*NN; \
      BF0[i_] = *(const f32x4*)(rp_ + n0_); \
      BF1[i_] = *(const f32x4*)(rp_ + n0_ + 4); \
      BMA[i_] = *(const f32x4*)(rp_ + 7996 - n0_); \
      BMB[i_] = *(const f32x4*)(rp_ + 7992 - n0_); \
      BMS[i_] = rp_[n0_ ? NN - n0_ : 0]; } }
  // fold + cvt + swizzled ds_write (r14-verified mirror element mapping)
  #define BWRITE(kt_, buf_) { int n0_ = (kt_)*64 + bs*8; \
    _Pragma("unroll") \
    for (int i_=0;i_<4;i_++){ \
      float pr_[8] = {BF0[i_][0],BF0[i_][1],BF0[i_][2],BF0[i_][3], \
                      BF1[i_][0],BF1[i_][1],BF1[i_][2],BF1[i_][3]}; \
      float mi_[8] = {n0_ ? BMS[i_] : 0.f, BMA[i_][3],BMA[i_][2],BMA[i_][1],BMA[i_][0], \
                      BMB[i_][3],BMB[i_][2],BMB[i_][1]}; \
      short8 o_; \
      _Pragma("unroll") \
      for (int e_=0;e_<8;e_++){ \
        int n_ = n0_ + e_; \
        float v_; \
        if (n_ == 0)          v_ = pr_[0]; \
        else if (n_ < 4000)   v_ = pr_[e_] + mi_[e_]; \
        else if (n_ == 4000)  v_ = pr_[e_]; \
        else                  v_ = 0.f; \
        o_[e_] = (short)bfc(v_); } \
      *(short8*)(&Bs[buf_][bw0 + i_*4096]) = o_; } }

  f32x16 acc[5][2];
  #pragma unroll
  for (int a=0;a<5;a++){ acc[a][0] = (f32x16)0.f; acc[a][1] = (f32x16)0.f; }

  // prologue: stage kt0
  BLOAD(kt0);
  AGLL(kt0, 0);
  asm volatile("s_waitcnt vmcnt(0)" ::: "memory");
  BWRITE(kt0, 0);
  asm volatile("s_waitcnt lgkmcnt(0)" ::: "memory");
  __builtin_amdgcn_s_barrier();
  __builtin_amdgcn_sched_barrier(0);

  int cur = 0;
  for (int kt = kt0; kt < ktE; ++kt){
    bool stg = (kt + 1 < ktE);
    if (stg){
      BLOAD(kt+1);                           // 20 loads, a full step early
      AGLL(kt+1, cur^1);                     // +5 GLL
    }
    __builtin_amdgcn_sched_barrier(0);
    const ushort* Ac = &As[cur][0];
    const ushort* Bc = &Bs[cur][0];
    #pragma unroll
    for (int p=0;p<4;p++){                   // 4 k=16 phases within BK=64
      short8 dfr[2];
      #pragma unroll
      for (int c=0;c<2;c++){
        int row = wn*64 + c*32 + l31;
        dfr[c] = *(const short8*)(Bc + row*64 + ((((p<<1)|lh) ^ (row & 7)) << 3));
      }
      short8 cfr[5];
      #pragma unroll
      for (int a=0;a<5;a++){
        int row = wm*160 + a*32 + l31;
        cfr[a] = *(const short8*)(Ac + row*64 + ((((p<<1)|lh) ^ (row & 7)) << 3));
      }
      __builtin_amdgcn_s_setprio(1);
      #pragma unroll
      for (int a=0;a<5;a++){
        acc[a][0] = __builtin_amdgcn_mfma_f32_32x32x16_bf16(dfr[0], cfr[a], acc[a][0], 0,0,0);
        acc[a][1] = __builtin_amdgcn_mfma_f32_32x32x16_bf16(dfr[1], cfr[a], acc[a][1], 0,0,0);
      }
      __builtin_amdgcn_s_setprio(0);
      if (p < 3){                            // phase lockstep (no vm drain)
        __builtin_amdgcn_sched_barrier(0);
        __builtin_amdgcn_s_barrier();
        __builtin_amdgcn_sched_barrier(0);
      }
    }
    if (stg){
      __builtin_amdgcn_sched_barrier(0);
      asm volatile("s_waitcnt vmcnt(0)" ::: "memory");   // B regs + A GLL landed
      BWRITE(kt+1, cur^1);
      asm volatile("s_waitcnt lgkmcnt(0)" ::: "memory"); // ds_writes visible
      __builtin_amdgcn_s_barrier();
      __builtin_amdgcn_sched_barrier(0);
    }
    cur ^= 1;
  }

  // D layout (32x32): n(q) = lane&31, m(col) = (r&3) + 8*(r>>2) + 4*(lane>>5)
  ushort* pb = part + (size_t)kc*NCOL*QPAD;
  #pragma unroll
  for (int a=0;a<5;a++){
    int q = qh*QH + wm*160 + a*32 + l31;
    #pragma unroll
    for (int c=0;c<2;c++){
      int colb = nb*BN + wn*64 + c*32 + 4*lh;
      #pragma unroll
      for (int r=0;r<16;r++){
        int col = colb + (r&3) + 8*(r>>2);
        pb[(size_t)col*QPAD + q] = bfc(acc[a][c][r]);
      }
    }
  }
}

// per (b,t) column: partial-sum + nonlinear -> fixed-width banded matvecs -> harmonic gather
__global__ __launch_bounds__(384) void fuse_k(const float* __restrict__ dx,
        const ushort* __restrict__ part,
        const float* __restrict__ WfT, const float* __restrict__ WqT,
        const int* __restrict__ fLo, const int* __restrict__ qLo,
        float* __restrict__ out, int HFI, int HQI){
  __shared__ float xr[2368];
  __shared__ float yq[QPAD];
  __shared__ float tl0[KBINS];
  __shared__ float tlq[KBINS];
  int col = blockIdx.x;
  int b = col >> 9, t = col & 511;
  int tid = threadIdx.x;
  const float invs = 0.011180339887498949f;   // 1/sqrt(8000)

  for (int f = tid; f < 2368; f += 384) xr[f] = (f < HFI) ? dx[(size_t)col*NN + f] : 0.f;
  const ushort* pc = part + (size_t)col*QPAD;
  for (int q = tid; q < QPAD; q += 384){
    float y = 0.f;
    if (q < HQI){
      float s = 0.f;
      #pragma unroll
      for (int kc=0; kc<KC; kc++) s += b2f(pc[(size_t)kc*NCOL*QPAD + q]);
      s *= invs;
      if (q >= CUTQ && s > 0.f) y = powf(s, 0.6f);
    }
    yq[q] = y;
  }
  __syncthreads();

  if (tid < KBINS){
    int k = tid;
    int lo = fLo[k];
    float aF = 0.f;
    #pragma unroll
    for (int j=0;j<WFB;j++) aF += WfT[j*KBINS + k] * xr[lo + j];
    int ql = qLo[k];
    float aQ = 0.f;
    #pragma unroll
    for (int j=0;j<WQB;j++) aQ += WqT[j*KBINS + k] * yq[ql + j];
    tl0[k] = aF; tlq[k] = aQ;
  }
  __syncthreads();

  const int hids[6] = {0,48,76,96,111,124};   // argmin|CF - (k+1)*27.5|
  for (int u = tid; u < 12*KBINS; u += 384){
    int j = u / KBINS;
    int k = u - j*KBINS;
    int h = hids[(j < 6) ? j : j - 6];
    float v;
    if (j < 6) v = (k + h < KBINS) ? tl0[k + h] : 0.f;   // har_s: shift left, pad end
    else       v = (k >= h)        ? tlq[k - h] : 0.f;   // har_c: shift right, pad front
    out[(((size_t)b*12 + j)*T_ + t)*KBINS + k] = v;
  }
}

extern "C" void kernel_launch(void* const* d_in, const int* in_sizes, int n_in,
                              void* d_out, int out_size, void* d_ws, size_t ws_size,
                              hipStream_t stream){
  const float* dx = (const float*)d_in[0];
  const float* Wf = (const float*)d_in[1];
  const float* Wq = (const float*)d_in[2];
  int HFI = in_sizes[1] / KBINS;   // runtime-derived (banker's-rounding safe)
  int HQI = in_sizes[2] / KBINS;
  float* out = (float*)d_out;
  char* ws = (char*)d_ws;

  ushort* cosg = (ushort*)ws;
  size_t off = (size_t)NTILE*QPAD*64*2;                        // 5.24 MB
  ushort* part = (ushort*)(ws + off); off += (size_t)KC*NCOL*QPAD*2;  // 41.94 MB
  int* fLo = (int*)(ws+off); off += KBINS*4;
  int* qLo = (int*)(ws+off); off += KBINS*4;
  float* WfT = (float*)(ws+off); off += (size_t)WFB*KBINS*4;   // 90 KB
  float* WqT = (float*)(ws+off); off += (size_t)WQB*KBINS*4;   // 28 KB
  (void)n_in; (void)out_size; (void)ws_size;

  prep_k<<<NCB + 2*KBINS, 256, 0, stream>>>(cosg, Wf, Wq, HFI, HQI, fLo, qLo, WfT, WqT);
  gemm_k<<<dim3(NCOL/BN, QPAD/QH, KC), 512, 0, stream>>>(dx, cosg, part);
  fuse_k<<<NCOL, 384, 0, stream>>>(dx, part, WfT, WqT, fLo, qLo, out, HFI, HQI);
}

// Round 18
// 132.248 us; speedup vs baseline: 1.2688x; 1.2688x over previous
//
#include <hip/hip_runtime.h>
#include <hip/hip_bf16.h>
#include <limits.h>

typedef __attribute__((ext_vector_type(8))) short short8;
typedef __attribute__((ext_vector_type(4))) float f32x4;
typedef __attribute__((ext_vector_type(4))) int i32x4;
typedef __attribute__((ext_vector_type(16))) float f32x16;

#define NN 8000
#define NCOL 4096      // 8*512 merged columns
#define KBINS 352      // NEST-1 == TOTAL_BINS
#define QPAD 640       // 583 padded
#define QH 320         // q rows per parity (u = q>>1)
#define BN 256         // cols per block
#define KC 8           // k chunks (grid 16x2x8 = 256 blocks = 1/CU)
#define NTILE 64       // K padded: 64 tiles of 64 (n>=4000 zeroed)
#define KSTEP 8        // tiles per chunk: 64 = 8*8 exact
#define XROW 4096      // xs row stride (ushorts), linear n-major
#define XPAR ((size_t)NCOL*XROW)   // parity stride in xs
#define CUTQ 4
#define T_ 512
#define WFB 64         // packed band width for W_freq
#define WQB 20         // packed band width for W_quef
#define NFB 4096       // prep: fold blocks (1 row each)
#define NCB 640        // prep: cos blocks (1 q each)

#define GLL16(g, l) __builtin_amdgcn_global_load_lds( \
    (const __attribute__((address_space(1))) unsigned int*)(g), \
    (__attribute__((address_space(3))) unsigned int*)(l), 16, 0, 0)

static __device__ __forceinline__ ushort bfc(float f){
  __hip_bfloat16 h = __float2bfloat16(f);
  return *reinterpret_cast<ushort*>(&h);
}
static __device__ __forceinline__ float b2f(ushort u){
  unsigned v = ((unsigned)u) << 16; float f; __builtin_memcpy(&f, &v, 4); return f;
}

// merged prep:
//  blocks [0,NFB): SHIFT-parity fold (pure streaming copy shape):
//      xe[n]=x[n]+x[n+4000], xo[n]=x[n]-x[n+4000] (n<4000; else 0), bf16,
//      stored LINEAR xs[par][row][n]. Both read streams forward-contiguous;
//      every store instruction is a contiguous 1KB wave store (lane stride 16B).
//      Boundary n=4000 falls exactly between threads (no edge cases).
//  blocks [NFB,NFB+NCB): per-parity cos table cosp[par][kt][u][64-swizzled]
//  rest: bounds-scan + transposed band-pack of Wf/Wq
__global__ __launch_bounds__(256) void prep_k(const float* __restrict__ dx,
        ushort* __restrict__ xs, ushort* __restrict__ cosp,
        const float* __restrict__ Wf, const float* __restrict__ Wq,
        int HFI, int HQI, int* __restrict__ fLo, int* __restrict__ qLo,
        float* __restrict__ WfT, float* __restrict__ WqT){
  int blk = blockIdx.x, t = threadIdx.x;
  if (blk < NFB){
    int row = blk;
    const float* rp = dx + (size_t)row*NN;
    ushort* xe = xs + (size_t)row*XROW;
    ushort* xo = xs + XPAR + (size_t)row*XROW;
    // two groups: n0 = g*2048 + t*8   (g=1,t>=244 -> n0>=4000 -> zeros)
    f32x4 A[2][2], B[2][2];
    int n0g[2]; bool live[2];
    #pragma unroll
    for (int g=0; g<2; ++g){
      int n0 = g*2048 + t*8;
      n0g[g] = n0; live[g] = (n0 < 4000);
      if (live[g]){
        A[g][0] = *(const f32x4*)(rp + n0);
        A[g][1] = *(const f32x4*)(rp + n0 + 4);
        B[g][0] = *(const f32x4*)(rp + 4000 + n0);
        B[g][1] = *(const f32x4*)(rp + 4000 + n0 + 4);
      }
    }
    #pragma unroll
    for (int g=0; g<2; ++g){
      short8 oe, oo;
      if (live[g]){
        #pragma unroll
        for (int i=0;i<2;i++){
          #pragma unroll
          for (int e=0;e<4;e++){
            float a = A[g][i][e], b = B[g][i][e];
            oe[4*i+e] = (short)bfc(a + b);
            oo[4*i+e] = (short)bfc(a - b);
          }
        }
      } else {
        #pragma unroll
        for (int e=0;e<8;e++){ oe[e] = 0; oo[e] = 0; }
      }
      *(short8*)(xe + n0g[g]) = oe;          // contiguous 1KB per wave store
      *(short8*)(xo + n0g[g]) = oo;
    }
  } else if (blk < NFB + NCB){
    int q = blk - NFB;
    int par = q & 1, u = q >> 1;
    int qz = (q < HQI) ? 1 : 0;
    #pragma unroll
    for (int h=0; h<2; ++h){                  // 2 octets per thread (16 n)
      int n0 = t*16 + h*8;                    // < 4096
      short8 o;
      #pragma unroll
      for (int e=0;e<8;e++){
        float v = 0.f;
        int n = n0 + e;
        if (qz && n < 4000){
          int m = (q*n) % NN;
          v = cosf((float)m * 7.8539816339744831e-4f);
        }
        o[e] = (short)bfc(v);
      }
      int kt = n0 >> 6, s8 = (n0 >> 3) & 7;
      *(short8*)(&cosp[((size_t)par*NTILE + kt)*(QH*64) + (size_t)u*64
                       + ((s8 ^ (u & 7)) << 3)]) = o;
    }
  } else {
    __shared__ int slo, shi;
    int u = blk - NFB - NCB;                  // 0..703
    int r = u >> 1;
    bool isF = (u & 1) == 0;
    const float* W = isF ? Wf : Wq;
    int width = isF ? HFI : HQI;
    int bw    = isF ? WFB : WQB;
    float* WT = isF ? WfT : WqT;
    int* Lo   = isF ? fLo : qLo;
    if (t==0){ slo = INT_MAX; shi = -1; }
    __syncthreads();
    int mylo = INT_MAX, myhi = -1;
    for (int c = t; c < width; c += 256){
      if (W[(size_t)r*width + c] != 0.f){ if (c < mylo) mylo = c; if (c > myhi) myhi = c; }
    }
    atomicMin(&slo, mylo); atomicMax(&shi, myhi);
    __syncthreads();
    int l = (shi < 0) ? 0 : slo, h = (shi < 0) ? 0 : shi + 1;
    if (t==0) Lo[r] = l;
    for (int j = t; j < bw; j += 256){
      float v = 0.f;
      if (l + j < h) v = W[(size_t)r*width + l + j];
      WT[(size_t)j*KBINS + r] = v;
    }
  }
}

// part[kc][col][par*320+u] (bf16) = sum_{k in chunk} xs[par][col][k]*cosp[par][u][k]
// Block 320u x 256col, BK=64, 8 waves (2 wm x 4 wn), wave tile 160u x 64col.
// dbuf 144KB LDS. A: GLL from pre-swizzled cosp (wave-linear). B: reg-staged from
// LINEAR xs (4x dwordx4 -> VGPR, swizzled ds_write after compute) [r16 replay-proven].
__global__ __launch_bounds__(512, 2) void gemm_k(const ushort* __restrict__ xs,
                                                 const ushort* __restrict__ cosp,
                                                 ushort* __restrict__ part){
  __shared__ ushort As[2][QH*64];    // cos tiles, 40 KB each, slot-swizzled
  __shared__ ushort Bs[2][BN*64];    // folded dx tiles, 32 KB each, slot-swizzled
  int tid = threadIdx.x;
  int nb = blockIdx.x, par = blockIdx.y, kc = blockIdx.z;
  int lane = tid & 63, widx = tid >> 6;
  int wm = widx & 1, wn = widx >> 1;
  int l31 = lane & 31, lh = lane >> 5;
  int kt0 = kc*KSTEP, ktE = kt0 + KSTEP;

  const ushort* ag0 = cosp + (size_t)par*(NTILE*QH*64) + tid*8;
  int brow0 = tid >> 3, bs = tid & 7;        // wave: 8 lanes/row = 128B contiguous
  const ushort* bg0 = xs + (size_t)par*XPAR + (size_t)(nb*BN + brow0)*XROW + bs*8;
  int bw0 = brow0*64 + ((bs ^ (brow0 & 7)) << 3);   // row&7 invariant under +64i

  i32x4 Breg[4];
  #define AGLL(kt_, buf_) { \
    const ushort* ag_ = ag0 + (size_t)(kt_)*(QH*64); \
    _Pragma("unroll") \
    for (int i_=0;i_<5;i_++) GLL16(ag_ + i_*4096, &As[buf_][tid*8 + i_*4096]); }
  #define BLOAD(kt_) { \
    _Pragma("unroll") \
    for (int i_=0;i_<4;i_++) Breg[i_] = *(const i32x4*)(bg0 + (size_t)i_*64*XROW + (kt_)*64); }
  #define BWRITE(buf_) { \
    _Pragma("unroll") \
    for (int i_=0;i_<4;i_++) *(i32x4*)(&Bs[buf_][bw0 + i_*4096]) = Breg[i_]; }

  f32x16 acc[5][2];
  #pragma unroll
  for (int a=0;a<5;a++){ acc[a][0] = (f32x16)0.f; acc[a][1] = (f32x16)0.f; }

  // prologue: stage kt0
  BLOAD(kt0);                                // oldest 4 vmem
  AGLL(kt0, 0);                              // +5
  asm volatile("s_waitcnt vmcnt(5)" ::: "memory");   // B loads landed
  BWRITE(0);
  asm volatile("s_waitcnt vmcnt(0) lgkmcnt(0)" ::: "memory");
  __builtin_amdgcn_s_barrier();
  __builtin_amdgcn_sched_barrier(0);

  int cur = 0;
  for (int kt = kt0; kt < ktE; ++kt){
    bool stg = (kt + 1 < ktE);
    if (stg){
      BLOAD(kt+1);                           // issue early (oldest 4)
      AGLL(kt+1, cur^1);                     // +5 -> 9 outstanding
    }
    __builtin_amdgcn_sched_barrier(0);
    const ushort* Ac = &As[cur][0];
    const ushort* Bc = &Bs[cur][0];
    #pragma unroll
    for (int p=0;p<4;p++){                   // 4 k=16 phases within BK=64
      short8 dfr[2];
      #pragma unroll
      for (int c=0;c<2;c++){
        int row = wn*64 + c*32 + l31;
        dfr[c] = *(const short8*)(Bc + row*64 + ((((p<<1)|lh) ^ (row & 7)) << 3));
      }
      short8 cfr[5];
      #pragma unroll
      for (int a=0;a<5;a++){
        int row = wm*160 + a*32 + l31;
        cfr[a] = *(const short8*)(Ac + row*64 + ((((p<<1)|lh) ^ (row & 7)) << 3));
      }
      __builtin_amdgcn_s_setprio(1);
      #pragma unroll
      for (int a=0;a<5;a++){
        acc[a][0] = __builtin_amdgcn_mfma_f32_32x32x16_bf16(dfr[0], cfr[a], acc[a][0], 0,0,0);
        acc[a][1] = __builtin_amdgcn_mfma_f32_32x32x16_bf16(dfr[1], cfr[a], acc[a][1], 0,0,0);
      }
      __builtin_amdgcn_s_setprio(0);
      if (p < 3){                            // phase lockstep (no vm drain)
        __builtin_amdgcn_sched_barrier(0);
        __builtin_amdgcn_s_barrier();
        __builtin_amdgcn_sched_barrier(0);
      }
    }
    if (stg){
      __builtin_amdgcn_sched_barrier(0);
      asm volatile("s_waitcnt vmcnt(5)" ::: "memory");   // B(kt+1) landed
      BWRITE(cur^1);
      asm volatile("s_waitcnt vmcnt(0) lgkmcnt(0)" ::: "memory");  // A-GLL + ds_write done
      __builtin_amdgcn_s_barrier();
      __builtin_amdgcn_sched_barrier(0);
    }
    cur ^= 1;
  }

  // D layout (32x32): n(u) = lane&31, m(col) = (r&3) + 8*(r>>2) + 4*(lane>>5)
  ushort* pb = part + (size_t)kc*NCOL*QPAD;
  #pragma unroll
  for (int a=0;a<5;a++){
    int slot = par*QH + wm*160 + a*32 + l31;        // q = 2u+par -> slot par*320+u
    #pragma unroll
    for (int c=0;c<2;c++){
      int colb = nb*BN + wn*64 + c*32 + 4*lh;
      #pragma unroll
      for (int r=0;r<16;r++){
        int col = colb + (r&3) + 8*(r>>2);
        pb[(size_t)col*QPAD + slot] = bfc(acc[a][c][r]);
      }
    }
  }
}

// per (b,t) column: partial-sum + nonlinear -> fixed-width banded matvecs -> harmonic gather
__global__ __launch_bounds__(384) void fuse_k(const float* __restrict__ dx,
        const ushort* __restrict__ part,
        const float* __restrict__ WfT, const float* __restrict__ WqT,
        const int* __restrict__ fLo, const int* __restrict__ qLo,
        float* __restrict__ out, int HFI, int HQI){
  __shared__ float xr[2368];
  __shared__ float yq[QPAD];
  __shared__ float tl0[KBINS];
  __shared__ float tlq[KBINS];
  int col = blockIdx.x;
  int b = col >> 9, t = col & 511;
  int tid = threadIdx.x;
  const float invs = 0.011180339887498949f;   // 1/sqrt(8000)

  for (int f = tid; f < 2368; f += 384) xr[f] = (f < HFI) ? dx[(size_t)col*NN + f] : 0.f;
  const ushort* pc = part + (size_t)col*QPAD;
  for (int q = tid; q < QPAD; q += 384){
    float y = 0.f;
    if (q < HQI){
      int slot = (q & 1)*QH + (q >> 1);       // parity-split slot mapping
      float s = 0.f;
      #pragma unroll
      for (int kc=0; kc<KC; kc++) s += b2f(pc[(size_t)kc*NCOL*QPAD + slot]);
      s *= invs;
      if (q >= CUTQ && s > 0.f) y = powf(s, 0.6f);
    }
    yq[q] = y;
  }
  __syncthreads();

  if (tid < KBINS){
    int k = tid;
    int lo = fLo[k];
    float aF = 0.f;
    #pragma unroll
    for (int j=0;j<WFB;j++) aF += WfT[j*KBINS + k] * xr[lo + j];
    int ql = qLo[k];
    float aQ = 0.f;
    #pragma unroll
    for (int j=0;j<WQB;j++) aQ += WqT[j*KBINS + k] * yq[ql + j];
    tl0[k] = aF; tlq[k] = aQ;
  }
  __syncthreads();

  const int hids[6] = {0,48,76,96,111,124};   // argmin|CF - (k+1)*27.5|
  for (int u = tid; u < 12*KBINS; u += 384){
    int j = u / KBINS;
    int k = u - j*KBINS;
    int h = hids[(j < 6) ? j : j - 6];
    float v;
    if (j < 6) v = (k + h < KBINS) ? tl0[k + h] : 0.f;   // har_s: shift left, pad end
    else       v = (k >= h)        ? tlq[k - h] : 0.f;   // har_c: shift right, pad front
    out[(((size_t)b*12 + j)*T_ + t)*KBINS + k] = v;
  }
}

extern "C" void kernel_launch(void* const* d_in, const int* in_sizes, int n_in,
                              void* d_out, int out_size, void* d_ws, size_t ws_size,
                              hipStream_t stream){
  const float* dx = (const float*)d_in[0];
  const float* Wf = (const float*)d_in[1];
  const float* Wq = (const float*)d_in[2];
  int HFI = in_sizes[1] / KBINS;   // runtime-derived (banker's-rounding safe)
  int HQI = in_sizes[2] / KBINS;
  float* out = (float*)d_out;
  char* ws = (char*)d_ws;

  ushort* cosp = (ushort*)ws;
  size_t off = (size_t)2*NTILE*QH*64*2;                        // 5.24 MB
  ushort* xs = (ushort*)(ws + off); off += (size_t)2*NCOL*XROW*2;     // 67.1 MB
  ushort* part = (ushort*)(ws + off); off += (size_t)KC*NCOL*QPAD*2;  // 41.94 MB
  int* fLo = (int*)(ws+off); off += KBINS*4;
  int* qLo = (int*)(ws+off); off += KBINS*4;
  float* WfT = (float*)(ws+off); off += (size_t)WFB*KBINS*4;   // 90 KB
  float* WqT = (float*)(ws+off); off += (size_t)WQB*KBINS*4;   // 28 KB
  (void)n_in; (void)out_size; (void)ws_size;

  prep_k<<<NFB + NCB + 2*KBINS, 256, 0, stream>>>(dx, xs, cosp, Wf, Wq,
                                                  HFI, HQI, fLo, qLo, WfT, WqT);
  gemm_k<<<dim3(NCOL/BN, 2, KC), 512, 0, stream>>>(xs, cosp, part);
  fuse_k<<<NCOL, 384, 0, stream>>>(dx, part, WfT, WqT, fLo, qLo, out, HFI, HQI);
}

// Round 19
// 125.071 us; speedup vs baseline: 1.3416x; 1.0574x over previous
//
#include <hip/hip_runtime.h>
#include <hip/hip_bf16.h>
#include <limits.h>

typedef __attribute__((ext_vector_type(8))) short short8;
typedef __attribute__((ext_vector_type(4))) float f32x4;
typedef __attribute__((ext_vector_type(4))) int i32x4;
typedef __attribute__((ext_vector_type(16))) float f32x16;

#define NN 8000
#define NCOL 4096      // 8*512 merged columns
#define KBINS 352      // NEST-1 == TOTAL_BINS
#define QPAD 640       // 583 padded
#define QH 320         // q rows per block (2 q-halves)
#define BN 256         // cols per block
#define KC 8           // k chunks (grid 16x2x8 = 256 blocks = 1/CU)
#define NTILE 64       // folded K padded: 64 tiles of 64 (n>4000 zeroed)
#define KSTEP 8        // tiles per chunk: 64 = 8*8 exact
#define XROW 4096      // xf row stride (ushorts) - linear n-major
#define CUTQ 4
#define T_ 512
#define WFB 64         // packed band width for W_freq
#define WQB 20         // packed band width for W_quef
#define NFB 4096       // prep: fold blocks (1 row each)
#define NCB 640        // prep: cos blocks (1 q each)

#define GLL16(g, l) __builtin_amdgcn_global_load_lds( \
    (const __attribute__((address_space(1))) unsigned int*)(g), \
    (__attribute__((address_space(3))) unsigned int*)(l), 16, 0, 0)

static __device__ __forceinline__ ushort bfc(float f){
  __hip_bfloat16 h = __float2bfloat16(f);
  return *reinterpret_cast<ushort*>(&h);
}
static __device__ __forceinline__ float b2f(ushort u){
  unsigned v = ((unsigned)u) << 16; float f; __builtin_memcpy(&f, &v, 4); return f;
}

// merged prep:
//  blocks [0,NFB): reflection fold -> xf[row][n] bf16, LINEAR n-major (pure
//    streaming both sides). Mirror stream read FORWARD (lane j loads the window
//    lane 63-j needs), exchanged via __shfl(.,63-l), reversed in-register.
//    xf[0]=x[0]; xf[n]=x[n]+x[8000-n] (1<=n<4000); xf[4000]=x[4000]; else 0.
//  blocks [NFB,NFB+NCB): cos table cosg[kt][q][64-swizzled] (gemm A operand)
//  rest: bounds-scan + transposed band-pack of Wf/Wq
__global__ __launch_bounds__(256) void prep_k(const float* __restrict__ dx,
        ushort* __restrict__ xf, ushort* __restrict__ cosg,
        const float* __restrict__ Wf, const float* __restrict__ Wq,
        int HFI, int HQI, int* __restrict__ fLo, int* __restrict__ qLo,
        float* __restrict__ WfT, float* __restrict__ WqT){
  int blk = blockIdx.x, t = threadIdx.x;
  if (blk < NFB){
    int row = blk;
    int w = t >> 6, l = t & 63;
    const float* rp = dx + (size_t)row*NN;
    ushort* xrow = xf + (size_t)row*XROW;
    f32x4 F0[2], F1[2], M0[2], M1[2];
    int n0g[2], N0g[2];
    #pragma unroll
    for (int g=0; g<2; ++g){
      int N0 = (2*w + g)*512;                 // 8 windows cover n in [0,4096)
      int n0 = N0 + 8*l;
      N0g[g] = N0; n0g[g] = n0;
      F0[g] = *(const f32x4*)(rp + n0);
      F1[g] = *(const f32x4*)(rp + n0 + 4);
      int mb = 8000 - N0 - 511 + 8*l;         // forward mirror window (4B-aligned)
      bool sh = (N0 == 0 && l == 63);         // avoid reading x[8000] (OOB on last row)
      M0[g] = *(const f32x4*)(rp + mb);
      M1[g] = *(const f32x4*)(rp + mb + (sh ? 3 : 4));
    }
    #pragma unroll
    for (int g=0; g<2; ++g){
      float a[8];
      #pragma unroll
      for (int i=0;i<4;i++) a[i]   = __shfl(M0[g][i], 63 - l, 64);
      #pragma unroll
      for (int i=0;i<4;i++) a[4+i] = __shfl(M1[g][i], 63 - l, 64);
      float fw[8] = {F0[g][0],F0[g][1],F0[g][2],F0[g][3],F1[g][0],F1[g][1],F1[g][2],F1[g][3]};
      bool comp = (N0g[g] == 0 && l == 0);    // received the shifted edge window
      short8 o;
      #pragma unroll
      for (int e=0;e<8;e++){
        int n = n0g[g] + e;
        int mi = 7 - e;                       // a[7-e] = x[8000-n]
        if (comp && e >= 1 && e <= 4) mi = 8 - e;   // shifted-data compensation
        float v;
        if (n == 0)          v = fw[0];
        else if (n < 4000)   v = fw[e] + a[mi];
        else if (n == 4000)  v = fw[e];
        else                 v = 0.f;
        o[e] = (short)bfc(v);
      }
      *(short8*)(xrow + n0g[g]) = o;          // wave-contiguous 1KB store
    }
  } else if (blk < NFB + NCB){
    int q = blk - NFB;
    int qz = (q < HQI) ? 1 : 0;
    #pragma unroll
    for (int h=0; h<2; ++h){                  // 2 octets per thread (16 n)
      int n0 = t*16 + h*8;                    // < 4096
      short8 o;
      #pragma unroll
      for (int e=0;e<8;e++){
        float v = 0.f;
        if (qz){
          int m = (q*(n0+e)) % NN;
          v = cosf((float)m * 7.8539816339744831e-4f);
        }
        o[e] = (short)bfc(v);
      }
      int kt = n0 >> 6, s8 = (n0 >> 3) & 7;
      *(short8*)(&cosg[(size_t)kt*(QPAD*64) + (size_t)q*64 + ((s8 ^ (q & 7)) << 3)]) = o;
    }
  } else {
    __shared__ int slo, shi;
    int u = blk - NFB - NCB;                  // 0..703
    int r = u >> 1;
    bool isF = (u & 1) == 0;
    const float* W = isF ? Wf : Wq;
    int width = isF ? HFI : HQI;
    int bw    = isF ? WFB : WQB;
    float* WT = isF ? WfT : WqT;
    int* Lo   = isF ? fLo : qLo;
    if (t==0){ slo = INT_MAX; shi = -1; }
    __syncthreads();
    int mylo = INT_MAX, myhi = -1;
    for (int c = t; c < width; c += 256){
      if (W[(size_t)r*width + c] != 0.f){ if (c < mylo) mylo = c; if (c > myhi) myhi = c; }
    }
    atomicMin(&slo, mylo); atomicMax(&shi, myhi);
    __syncthreads();
    int l = (shi < 0) ? 0 : slo, h = (shi < 0) ? 0 : shi + 1;
    if (t==0) Lo[r] = l;
    for (int j = t; j < bw; j += 256){
      float v = 0.f;
      if (l + j < h) v = W[(size_t)r*width + l + j];
      WT[(size_t)j*KBINS + r] = v;
    }
  }
}

// part[kc][col][q] (bf16) = sum_{k in chunk} xf[col][k]*cosg[q][k]
// Block 320q x 256col, BK=64, 8 waves (2 wm x 4 wn), wave tile 160q x 64col.
// dbuf 144KB LDS. A: GLL from pre-swizzled cosg (wave-linear). B: reg-staged
// from LINEAR n-major xf (4x dwordx4 -> VGPR, swizzled ds_write after compute).
// Waits: vmcnt(5) before B ds_write, vmcnt(0)+lgkmcnt(0) before barrier.
__global__ __launch_bounds__(512, 2) void gemm_k(const ushort* __restrict__ xf,
                                                 const ushort* __restrict__ cosg,
                                                 ushort* __restrict__ part){
  __shared__ ushort As[2][QH*64];    // cos tiles, 40 KB each, slot-swizzled
  __shared__ ushort Bs[2][BN*64];    // folded dx tiles, 32 KB each, slot-swizzled
  int tid = threadIdx.x;
  int nb = blockIdx.x, qh = blockIdx.y, kc = blockIdx.z;
  int lane = tid & 63, widx = tid >> 6;
  int wm = widx & 1, wn = widx >> 1;
  int l31 = lane & 31, lh = lane >> 5;
  int kt0 = kc*KSTEP, ktE = kt0 + KSTEP;

  const ushort* ag0 = cosg + (size_t)qh*(QH*64) + tid*8;
  int brow0 = tid >> 3, bs = tid & 7;        // wave: 8 lanes/row = 128B contiguous
  const ushort* bg0 = xf + ((size_t)(nb*BN + brow0))*XROW + bs*8;
  int bw0 = brow0*64 + ((bs ^ (brow0 & 7)) << 3);   // row&7 invariant under +64i

  i32x4 Breg[4];
  #define AGLL(kt_, buf_) { \
    const ushort* ag_ = ag0 + (size_t)(kt_)*(QPAD*64); \
    _Pragma("unroll") \
    for (int i_=0;i_<5;i_++) GLL16(ag_ + i_*4096, &As[buf_][tid*8 + i_*4096]); }
  #define BLOAD(kt_) { \
    _Pragma("unroll") \
    for (int i_=0;i_<4;i_++) Breg[i_] = *(const i32x4*)(bg0 + (size_t)i_*64*XROW + (kt_)*64); }
  #define BWRITE(buf_) { \
    _Pragma("unroll") \
    for (int i_=0;i_<4;i_++) *(i32x4*)(&Bs[buf_][bw0 + i_*4096]) = Breg[i_]; }

  f32x16 acc[5][2];
  #pragma unroll
  for (int a=0;a<5;a++){ acc[a][0] = (f32x16)0.f; acc[a][1] = (f32x16)0.f; }

  // prologue: stage kt0
  BLOAD(kt0);                                // oldest 4 vmem
  AGLL(kt0, 0);                              // +5
  asm volatile("s_waitcnt vmcnt(5)" ::: "memory");   // B loads landed
  BWRITE(0);
  asm volatile("s_waitcnt vmcnt(0) lgkmcnt(0)" ::: "memory");
  __builtin_amdgcn_s_barrier();
  __builtin_amdgcn_sched_barrier(0);

  int cur = 0;
  for (int kt = kt0; kt < ktE; ++kt){
    bool stg = (kt + 1 < ktE);
    if (stg){
      BLOAD(kt+1);                           // issue early (oldest 4)
      AGLL(kt+1, cur^1);                     // +5 -> 9 outstanding
    }
    __builtin_amdgcn_sched_barrier(0);
    const ushort* Ac = &As[cur][0];
    const ushort* Bc = &Bs[cur][0];
    #pragma unroll
    for (int p=0;p<4;p++){                   // 4 k=16 phases within BK=64
      short8 dfr[2];
      #pragma unroll
      for (int c=0;c<2;c++){
        int row = wn*64 + c*32 + l31;
        dfr[c] = *(const short8*)(Bc + row*64 + ((((p<<1)|lh) ^ (row & 7)) << 3));
      }
      short8 cfr[5];
      #pragma unroll
      for (int a=0;a<5;a++){
        int row = wm*160 + a*32 + l31;
        cfr[a] = *(const short8*)(Ac + row*64 + ((((p<<1)|lh) ^ (row & 7)) << 3));
      }
      __builtin_amdgcn_s_setprio(1);
      #pragma unroll
      for (int a=0;a<5;a++){
        acc[a][0] = __builtin_amdgcn_mfma_f32_32x32x16_bf16(dfr[0], cfr[a], acc[a][0], 0,0,0);
        acc[a][1] = __builtin_amdgcn_mfma_f32_32x32x16_bf16(dfr[1], cfr[a], acc[a][1], 0,0,0);
      }
      __builtin_amdgcn_s_setprio(0);
      if (p < 3){                            // phase lockstep (no vm drain)
        __builtin_amdgcn_sched_barrier(0);
        __builtin_amdgcn_s_barrier();
        __builtin_amdgcn_sched_barrier(0);
      }
    }
    if (stg){
      __builtin_amdgcn_sched_barrier(0);
      asm volatile("s_waitcnt vmcnt(5)" ::: "memory");   // B(kt+1) landed
      BWRITE(cur^1);
      asm volatile("s_waitcnt vmcnt(0) lgkmcnt(0)" ::: "memory");  // A-GLL + ds_write done
      __builtin_amdgcn_s_barrier();
      __builtin_amdgcn_sched_barrier(0);
    }
    cur ^= 1;
  }

  // D layout (32x32): n(q) = lane&31, m(col) = (r&3) + 8*(r>>2) + 4*(lane>>5)
  ushort* pb = part + (size_t)kc*NCOL*QPAD;
  #pragma unroll
  for (int a=0;a<5;a++){
    int q = qh*QH + wm*160 + a*32 + l31;
    #pragma unroll
    for (int c=0;c<2;c++){
      int colb = nb*BN + wn*64 + c*32 + 4*lh;
      #pragma unroll
      for (int r=0;r<16;r++){
        int col = colb + (r&3) + 8*(r>>2);
        pb[(size_t)col*QPAD + q] = bfc(acc[a][c][r]);
      }
    }
  }
}

// per (b,t) column: partial-sum + nonlinear -> fixed-width banded matvecs -> harmonic gather
__global__ __launch_bounds__(384) void fuse_k(const float* __restrict__ dx,
        const ushort* __restrict__ part,
        const float* __restrict__ WfT, const float* __restrict__ WqT,
        const int* __restrict__ fLo, const int* __restrict__ qLo,
        float* __restrict__ out, int HFI, int HQI){
  __shared__ float xr[2368];
  __shared__ float yq[QPAD];
  __shared__ float tl0[KBINS];
  __shared__ float tlq[KBINS];
  int col = blockIdx.x;
  int b = col >> 9, t = col & 511;
  int tid = threadIdx.x;
  const float invs = 0.011180339887498949f;   // 1/sqrt(8000)

  for (int f = tid; f < 2368; f += 384) xr[f] = (f < HFI) ? dx[(size_t)col*NN + f] : 0.f;
  const ushort* pc = part + (size_t)col*QPAD;
  for (int q = tid; q < QPAD; q += 384){
    float y = 0.f;
    if (q < HQI){
      float s = 0.f;
      #pragma unroll
      for (int kc=0; kc<KC; kc++) s += b2f(pc[(size_t)kc*NCOL*QPAD + q]);
      s *= invs;
      if (q >= CUTQ && s > 0.f) y = powf(s, 0.6f);
    }
    yq[q] = y;
  }
  __syncthreads();

  if (tid < KBINS){
    int k = tid;
    int lo = fLo[k];
    float aF = 0.f;
    #pragma unroll
    for (int j=0;j<WFB;j++) aF += WfT[j*KBINS + k] * xr[lo + j];
    int ql = qLo[k];
    float aQ = 0.f;
    #pragma unroll
    for (int j=0;j<WQB;j++) aQ += WqT[j*KBINS + k] * yq[ql + j];
    tl0[k] = aF; tlq[k] = aQ;
  }
  __syncthreads();

  const int hids[6] = {0,48,76,96,111,124};   // argmin|CF - (k+1)*27.5|
  for (int u = tid; u < 12*KBINS; u += 384){
    int j = u / KBINS;
    int k = u - j*KBINS;
    int h = hids[(j < 6) ? j : j - 6];
    float v;
    if (j < 6) v = (k + h < KBINS) ? tl0[k + h] : 0.f;   // har_s: shift left, pad end
    else       v = (k >= h)        ? tlq[k - h] : 0.f;   // har_c: shift right, pad front
    out[(((size_t)b*12 + j)*T_ + t)*KBINS + k] = v;
  }
}

extern "C" void kernel_launch(void* const* d_in, const int* in_sizes, int n_in,
                              void* d_out, int out_size, void* d_ws, size_t ws_size,
                              hipStream_t stream){
  const float* dx = (const float*)d_in[0];
  const float* Wf = (const float*)d_in[1];
  const float* Wq = (const float*)d_in[2];
  int HFI = in_sizes[1] / KBINS;   // runtime-derived (banker's-rounding safe)
  int HQI = in_sizes[2] / KBINS;
  float* out = (float*)d_out;
  char* ws = (char*)d_ws;

  ushort* cosg = (ushort*)ws;
  size_t off = (size_t)NTILE*QPAD*64*2;                        // 5.24 MB
  ushort* xf = (ushort*)(ws + off); off += (size_t)NCOL*XROW*2;       // 33.55 MB (linear)
  ushort* part = (ushort*)(ws + off); off += (size_t)KC*NCOL*QPAD*2;  // 41.94 MB
  int* fLo = (int*)(ws+off); off += KBINS*4;
  int* qLo = (int*)(ws+off); off += KBINS*4;
  float* WfT = (float*)(ws+off); off += (size_t)WFB*KBINS*4;   // 90 KB
  float* WqT = (float*)(ws+off); off += (size_t)WQB*KBINS*4;   // 28 KB
  (void)n_in; (void)out_size; (void)ws_size;

  prep_k<<<NFB + NCB + 2*KBINS, 256, 0, stream>>>(dx, xf, cosg, Wf, Wq,
                                                  HFI, HQI, fLo, qLo, WfT, WqT);
  gemm_k<<<dim3(NCOL/BN, QPAD/QH, KC), 512, 0, stream>>>(xf, cosg, part);
  fuse_k<<<NCOL, 384, 0, stream>>>(dx, part, WfT, WqT, fLo, qLo, out, HFI, HQI);
}